// Round 9
// baseline (229.212 us; speedup 1.0000x reference)
//
#include <hip/hip_runtime.h>
#include <hip/hip_bf16.h>
#include <math.h>

#define H 128
#define EPS 1e-5f
#define INF_BIAS 0.1f

typedef __attribute__((ext_vector_type(8))) short bf16x8;
typedef __attribute__((ext_vector_type(4))) float f32x4;

// ---- bf16 helpers (RNE) ----
__device__ inline unsigned short f2bf_rne(float f) {
    unsigned u = __float_as_uint(f);
    u += 0x7fffu + ((u >> 16) & 1u);
    return (unsigned short)(u >> 16);
}
__device__ inline float bf2f(unsigned short h) {
    return __uint_as_float(((unsigned)h) << 16);
}
__device__ inline unsigned pack2(float a, float b) {
    return (unsigned)f2bf_rne(a) | ((unsigned)f2bf_rne(b) << 16);
}
__device__ inline float2 unpack2(unsigned v) {
    float2 r;
    r.x = __uint_as_float(v << 16);
    r.y = __uint_as_float(v & 0xffff0000u);
    return r;
}

// ---------------------------------------------------------------------------
// prep: BN-prescaled bf16 W in MFMA A-fragment order with a PERMUTED j->m
// mapping chosen so the proj epilogue is contiguous:
//   frag f = half*16 + nt*4 + kt; lane t = q*16+c holds
//   j = half*64 + (c>>2)*16 + nt*4 + (c&3), k = kt*32+q*8..+8
// ---------------------------------------------------------------------------
__global__ void prep_kernel(
    const float* __restrict__ W1, const float* __restrict__ b1,
    const float* __restrict__ gamma, const float* __restrict__ beta,
    const float* __restrict__ rm, const float* __restrict__ rv,
    unsigned short* __restrict__ Wswz_u, unsigned short* __restrict__ Wswz_f,
    float* __restrict__ d_user)
{
    const int f    = blockIdx.x;          // 0..31
    const int half = f >> 4, nt = (f >> 2) & 3, kt = f & 3;
    const int t    = threadIdx.x;         // 0..63
    const int c    = t & 15, q = t >> 4;

    const int j  = half * 64 + (c >> 2) * 16 + nt * 4 + (c & 3);
    const float a = gamma[j] * rsqrtf(rv[j] + EPS);
    const int k0 = kt * 32 + q * 8;

    unsigned short wu[8], wf[8];
    #pragma unroll
    for (int i = 0; i < 8; ++i) {
        wu[i] = f2bf_rne(a * W1[(size_t)j * (2 * H) + k0 + i]);
        wf[i] = f2bf_rne(a * W1[(size_t)j * (2 * H) + H + k0 + i]);
    }
    const size_t dst = (size_t)f * 512 + (size_t)t * 8;   // ushort units
    #pragma unroll
    for (int i = 0; i < 8; ++i) { Wswz_u[dst + i] = wu[i]; Wswz_f[dst + i] = wf[i]; }

    if (kt == 0 && q == 0) d_user[j] = a * (b1[j] - rm[j]) + beta[j];
}

// ---------------------------------------------------------------------------
// proj_mfma v6: W register-stationary + MULTI-TILE per block.
// Block owns a contiguous 128-row chunk (8 tiles). Wave (half, tilepar)
// computes col-half `half` of tiles {tilepar, tilepar+2, ...} (4 tiles),
// amortizing the 16-fragment W preload 4x. No barriers; compiler pipelines
// Z loads across tile iterations. Permuted-j frags -> contiguous 2x16B
// stores. Z split hi+lo bf16 (2 MFMAs) - arithmetic identical to R4-R8.
// ---------------------------------------------------------------------------
#define TPB 8   // tiles (16 rows) per block
__global__ __launch_bounds__(256, 4) void proj_mfma(
    const float* __restrict__ z_user, const float* __restrict__ z_food,
    const unsigned short* __restrict__ Wswz_u, const unsigned short* __restrict__ Wswz_f,
    const float* __restrict__ d_user,
    unsigned short* __restrict__ U, unsigned short* __restrict__ F,
    int n_users, int n_foods, int GU)
{
    const bool userMode = (blockIdx.x < (unsigned)GU);
    const float* Z;
    const unsigned short* Wsrc;
    unsigned short* Out;
    int n, blk0;
    if (userMode) { Z = z_user; Wsrc = Wswz_u; Out = U; n = n_users; blk0 = blockIdx.x; }
    else          { Z = z_food; Wsrc = Wswz_f; Out = F; n = n_foods; blk0 = blockIdx.x - GU; }
    const int tiles = n >> 4;   // n divisible by 16

    const int wave = threadIdx.x >> 6;
    const int lane = threadIdx.x & 63;
    const int c = lane & 15;        // B n-index -> row within tile
    const int q = lane >> 4;        // k-group / 16-col subgroup
    const int half    = wave & 1;   // 64-col half
    const int tilepar = wave >> 1;  // starting tile parity within chunk

    // ---- preload this wave's 16 W fragments (64 VGPR), L2-hot
    bf16x8 wf[4][4];
    #pragma unroll
    for (int nt = 0; nt < 4; ++nt)
        #pragma unroll
        for (int kt = 0; kt < 4; ++kt)
            wf[nt][kt] = *(const bf16x8*)(Wsrc + (size_t)(half * 16 + nt * 4 + kt) * 512 + lane * 8);

    // ---- BN offset (accumulator init values)
    f32x4 dvec[4];
    #pragma unroll
    for (int nt = 0; nt < 4; ++nt) {
        if (userMode) {
            float4 d = *(const float4*)(d_user + half * 64 + q * 16 + nt * 4);
            dvec[nt] = (f32x4){d.x, d.y, d.z, d.w};
        } else {
            dvec[nt] = (f32x4){0.f, 0.f, 0.f, 0.f};
        }
    }

    #pragma unroll
    for (int it = 0; it < TPB / 2; ++it) {
        const int t = blk0 * TPB + tilepar + it * 2;
        if (t >= tiles) break;

        const int r = t * 16 + c;
        const float* zrow = Z + (size_t)r * H;

        f32x4 acc[4];
        #pragma unroll
        for (int nt = 0; nt < 4; ++nt) acc[nt] = dvec[nt];

        #pragma unroll
        for (int kt = 0; kt < 4; ++kt) {
            const int k0 = kt * 32 + q * 8;
            float4 za = ((const float4*)(zrow + k0))[0];
            float4 zb = ((const float4*)(zrow + k0))[1];
            bf16x8 zhi, zlo;
            {
                float v[8] = {za.x, za.y, za.z, za.w, zb.x, zb.y, zb.z, zb.w};
                #pragma unroll
                for (int i = 0; i < 8; ++i) {
                    unsigned short hi = f2bf_rne(v[i]);
                    unsigned short lo = f2bf_rne(v[i] - bf2f(hi));
                    zhi[i] = (short)hi; zlo[i] = (short)lo;
                }
            }
            #pragma unroll
            for (int nt = 0; nt < 4; ++nt) {
                acc[nt] = __builtin_amdgcn_mfma_f32_16x16x32_bf16(wf[nt][kt], zhi, acc[nt], 0, 0, 0);
                acc[nt] = __builtin_amdgcn_mfma_f32_16x16x32_bf16(wf[nt][kt], zlo, acc[nt], 0, 0, 0);
            }
        }

        // contiguous epilogue: lane (c,q) owns cols half*64+q*16 .. +16 of row r
        unsigned short* obase = Out + (size_t)r * H + half * 64 + q * 16;
        uint4 p0, p1;
        p0.x = pack2(acc[0][0], acc[0][1]); p0.y = pack2(acc[0][2], acc[0][3]);
        p0.z = pack2(acc[1][0], acc[1][1]); p0.w = pack2(acc[1][2], acc[1][3]);
        p1.x = pack2(acc[2][0], acc[2][1]); p1.y = pack2(acc[2][2], acc[2][3]);
        p1.z = pack2(acc[3][0], acc[3][1]); p1.w = pack2(acc[3][2], acc[3][3]);
        *(uint4*)(obase)     = p0;
        *(uint4*)(obase + 8) = p1;
    }
}

// ---------------------------------------------------------------------------
// edge kernel v2 (unchanged from round 8): 4-way unrolled gather.
// ---------------------------------------------------------------------------
#define EUN 4
__global__ __launch_bounds__(256) void edge_kernel(
    const unsigned short* __restrict__ U, const unsigned short* __restrict__ F,
    const int* __restrict__ row, const int* __restrict__ col,
    const float* __restrict__ W2, const float* __restrict__ b2,
    float* __restrict__ out, int E)
{
    const int lane = threadIdx.x & 15;
    const int g  = (blockIdx.x * blockDim.x + threadIdx.x) >> 4;
    const int nG = (gridDim.x * blockDim.x) >> 4;

    const float4 w2a = ((const float4*)W2)[2 * lane];
    const float4 w2b = ((const float4*)W2)[2 * lane + 1];
    const float bias = b2[0] + INF_BIAS;

    for (int e0 = g; e0 < E; e0 += EUN * nG) {
        int iu[EUN], ifo[EUN];
        #pragma unroll
        for (int i = 0; i < EUN; ++i) {
            int e  = e0 + i * nG;
            int ec = (e < E) ? e : e0;
            iu[i]  = row[ec];
            ifo[i] = col[ec];
        }
        uint4 uv[EUN], fv[EUN];
        #pragma unroll
        for (int i = 0; i < EUN; ++i) {
            uv[i] = ((const uint4*)(U + (size_t)iu[i]  * H))[lane];
            fv[i] = ((const uint4*)(F + (size_t)ifo[i] * H))[lane];
        }
        #pragma unroll
        for (int i = 0; i < EUN; ++i) {
            float2 u0 = unpack2(uv[i].x), f0 = unpack2(fv[i].x);
            float2 u1 = unpack2(uv[i].y), f1 = unpack2(fv[i].y);
            float2 u2 = unpack2(uv[i].z), f2 = unpack2(fv[i].z);
            float2 u3 = unpack2(uv[i].w), f3 = unpack2(fv[i].w);

            float s =
                w2a.x * fmaxf(u0.x + f0.x, 0.0f) +
                w2a.y * fmaxf(u0.y + f0.y, 0.0f) +
                w2a.z * fmaxf(u1.x + f1.x, 0.0f) +
                w2a.w * fmaxf(u1.y + f1.y, 0.0f) +
                w2b.x * fmaxf(u2.x + f2.x, 0.0f) +
                w2b.y * fmaxf(u2.y + f2.y, 0.0f) +
                w2b.z * fmaxf(u3.x + f3.x, 0.0f) +
                w2b.w * fmaxf(u3.y + f3.y, 0.0f);

            s += __shfl_xor(s, 8, 16);
            s += __shfl_xor(s, 4, 16);
            s += __shfl_xor(s, 2, 16);
            s += __shfl_xor(s, 1, 16);

            const int e = e0 + i * nG;
            if (lane == 0 && e < E) {
                float x = s + bias;
                out[e] = 1.0f / (1.0f + __expf(-x));
            }
        }
    }
}

extern "C" void kernel_launch(void* const* d_in, const int* in_sizes, int n_in,
                              void* d_out, int out_size, void* d_ws, size_t ws_size,
                              hipStream_t stream) {
    const float* z_user = (const float*)d_in[0];
    const float* z_food = (const float*)d_in[1];
    const int*   row    = (const int*)d_in[2];
    const int*   col    = (const int*)d_in[3];
    const float* W1     = (const float*)d_in[4];
    const float* b1     = (const float*)d_in[5];
    const float* gamma  = (const float*)d_in[6];
    const float* beta   = (const float*)d_in[7];
    const float* rm     = (const float*)d_in[8];
    const float* rv     = (const float*)d_in[9];
    const float* W2     = (const float*)d_in[10];
    const float* b2     = (const float*)d_in[11];
    float* out = (float*)d_out;

    const int n_users = in_sizes[0] / H;
    const int n_foods = in_sizes[1] / H;
    const int E       = in_sizes[2];

    // workspace layout
    unsigned short* U      = (unsigned short*)d_ws;        // n_users*128 bf16
    unsigned short* F      = U + (size_t)n_users * H;      // n_foods*128 bf16
    unsigned short* Wswz_u = F + (size_t)n_foods * H;      // 128*128 bf16, frag order
    unsigned short* Wswz_f = Wswz_u + H * H;               // 128*128 bf16, frag order
    float*          d_usr  = (float*)(Wswz_f + H * H);     // 128 f32

    prep_kernel<<<32, 64, 0, stream>>>(W1, b1, gamma, beta, rm, rv,
                                       Wswz_u, Wswz_f, d_usr);

    // one contiguous 128-row (8-tile) chunk per block
    const int GU = (n_users + 16 * TPB - 1) / (16 * TPB);   // 782
    const int GF = (n_foods + 16 * TPB - 1) / (16 * TPB);   // 391
    proj_mfma<<<GU + GF, 256, 0, stream>>>(z_user, z_food, Wswz_u, Wswz_f, d_usr,
                                           U, F, n_users, n_foods, GU);

    edge_kernel<<<8192, 256, 0, stream>>>(U, F, row, col, W2, b2, out, E);
}

// Round 10
// 211.388 us; speedup vs baseline: 1.0843x; 1.0843x over previous
//
#include <hip/hip_runtime.h>
#include <hip/hip_bf16.h>
#include <math.h>

#define H 128
#define EPS 1e-5f
#define INF_BIAS 0.1f

typedef __attribute__((ext_vector_type(8))) short bf16x8;
typedef __attribute__((ext_vector_type(4))) float f32x4;

// ---- bf16 helpers (RNE) ----
__device__ inline unsigned short f2bf_rne(float f) {
    unsigned u = __float_as_uint(f);
    u += 0x7fffu + ((u >> 16) & 1u);
    return (unsigned short)(u >> 16);
}
__device__ inline float bf2f(unsigned short h) {
    return __uint_as_float(((unsigned)h) << 16);
}
__device__ inline unsigned pack2(float a, float b) {
    return (unsigned)f2bf_rne(a) | ((unsigned)f2bf_rne(b) << 16);
}
__device__ inline float2 unpack2(unsigned v) {
    float2 r;
    r.x = __uint_as_float(v << 16);
    r.y = __uint_as_float(v & 0xffff0000u);
    return r;
}

// ---------------------------------------------------------------------------
// prep: BN-prescaled bf16 W in MFMA A-fragment order with a PERMUTED j->m
// mapping chosen so the proj epilogue is contiguous:
//   frag f = half*16 + nt*4 + kt; lane t = q*16+c holds
//   j = half*64 + (c>>2)*16 + nt*4 + (c&3), k = kt*32+q*8..+8
// ---------------------------------------------------------------------------
__global__ void prep_kernel(
    const float* __restrict__ W1, const float* __restrict__ b1,
    const float* __restrict__ gamma, const float* __restrict__ beta,
    const float* __restrict__ rm, const float* __restrict__ rv,
    unsigned short* __restrict__ Wswz_u, unsigned short* __restrict__ Wswz_f,
    float* __restrict__ d_user)
{
    const int f    = blockIdx.x;          // 0..31
    const int half = f >> 4, nt = (f >> 2) & 3, kt = f & 3;
    const int t    = threadIdx.x;         // 0..63
    const int c    = t & 15, q = t >> 4;

    const int j  = half * 64 + (c >> 2) * 16 + nt * 4 + (c & 3);
    const float a = gamma[j] * rsqrtf(rv[j] + EPS);
    const int k0 = kt * 32 + q * 8;

    unsigned short wu[8], wf[8];
    #pragma unroll
    for (int i = 0; i < 8; ++i) {
        wu[i] = f2bf_rne(a * W1[(size_t)j * (2 * H) + k0 + i]);
        wf[i] = f2bf_rne(a * W1[(size_t)j * (2 * H) + H + k0 + i]);
    }
    const size_t dst = (size_t)f * 512 + (size_t)t * 8;   // ushort units
    #pragma unroll
    for (int i = 0; i < 8; ++i) { Wswz_u[dst + i] = wu[i]; Wswz_f[dst + i] = wf[i]; }

    if (kt == 0 && q == 0) d_user[j] = a * (b1[j] - rm[j]) + beta[j];
}

// ---------------------------------------------------------------------------
// proj_mfma v7: two tiles per wave, ALL Z loads hoisted before any compute.
// Block = 64 contiguous rows (4 tiles). Wave (half, par) computes col-half
// `half` of tiles {blk*4+par, blk*4+par+2}. Both tiles' Z (16 x 16B/lane)
// load back-to-back -> 16 outstanding vmem per wave, no serialization, no
// barriers. Per-tile arithmetic bit-identical to R7 (W-hi, Z hi+lo split,
// kt-outer/nt-inner MFMA order, permuted-j contiguous 2x16B stores).
// ---------------------------------------------------------------------------
__global__ __launch_bounds__(256, 2) void proj_mfma(
    const float* __restrict__ z_user, const float* __restrict__ z_food,
    const unsigned short* __restrict__ Wswz_u, const unsigned short* __restrict__ Wswz_f,
    const float* __restrict__ d_user,
    unsigned short* __restrict__ U, unsigned short* __restrict__ F,
    int n_users, int n_foods, int GU)
{
    const bool userMode = (blockIdx.x < (unsigned)GU);
    const float* Z;
    const unsigned short* Wsrc;
    unsigned short* Out;
    int n, blk0;
    if (userMode) { Z = z_user; Wsrc = Wswz_u; Out = U; n = n_users; blk0 = blockIdx.x; }
    else          { Z = z_food; Wsrc = Wswz_f; Out = F; n = n_foods; blk0 = blockIdx.x - GU; }
    const int tiles = n >> 4;   // n divisible by 16

    const int wave = threadIdx.x >> 6;
    const int lane = threadIdx.x & 63;
    const int c = lane & 15;        // row within tile
    const int q = lane >> 4;        // k-group / 16-col subgroup
    const int half = wave & 1;      // 64-col half
    const int par  = wave >> 1;     // tile parity within chunk

    const int tT[2] = { blk0 * 4 + par, blk0 * 4 + par + 2 };
    const bool vT[2] = { tT[0] < tiles, tT[1] < tiles };
    const int rT[2] = { min(tT[0], tiles - 1) * 16 + c,
                        min(tT[1], tiles - 1) * 16 + c };

    // ---- preload this wave's 16 W fragments (64 VGPR) from the L2-hot table
    bf16x8 wf[4][4];
    #pragma unroll
    for (int nt = 0; nt < 4; ++nt)
        #pragma unroll
        for (int kt = 0; kt < 4; ++kt)
            wf[nt][kt] = *(const bf16x8*)(Wsrc + (size_t)(half * 16 + nt * 4 + kt) * 512 + lane * 8);

    // ---- BN offset (accumulator init values)
    f32x4 dvec[4];
    #pragma unroll
    for (int nt = 0; nt < 4; ++nt) {
        if (userMode) {
            float4 d = *(const float4*)(d_user + half * 64 + q * 16 + nt * 4);
            dvec[nt] = (f32x4){d.x, d.y, d.z, d.w};
        } else {
            dvec[nt] = (f32x4){0.f, 0.f, 0.f, 0.f};
        }
    }

    // ---- hoist ALL Z loads for both tiles (16 x 16B per lane, independent)
    float4 zv[2][4][2];
    #pragma unroll
    for (int tt = 0; tt < 2; ++tt) {
        const float* zrow = Z + (size_t)rT[tt] * H;
        #pragma unroll
        for (int kt = 0; kt < 4; ++kt) {
            const int k0 = kt * 32 + q * 8;
            zv[tt][kt][0] = ((const float4*)(zrow + k0))[0];
            zv[tt][kt][1] = ((const float4*)(zrow + k0))[1];
        }
    }

    // ---- process each tile (bit-identical to R7 per-tile arithmetic)
    #pragma unroll
    for (int tt = 0; tt < 2; ++tt) {
        f32x4 acc[4];
        #pragma unroll
        for (int nt = 0; nt < 4; ++nt) acc[nt] = dvec[nt];

        #pragma unroll
        for (int kt = 0; kt < 4; ++kt) {
            float4 za = zv[tt][kt][0];
            float4 zb = zv[tt][kt][1];
            bf16x8 zhi, zlo;
            {
                float v[8] = {za.x, za.y, za.z, za.w, zb.x, zb.y, zb.z, zb.w};
                #pragma unroll
                for (int i = 0; i < 8; ++i) {
                    unsigned short hi = f2bf_rne(v[i]);
                    unsigned short lo = f2bf_rne(v[i] - bf2f(hi));
                    zhi[i] = (short)hi; zlo[i] = (short)lo;
                }
            }
            #pragma unroll
            for (int nt = 0; nt < 4; ++nt) {
                acc[nt] = __builtin_amdgcn_mfma_f32_16x16x32_bf16(wf[nt][kt], zhi, acc[nt], 0, 0, 0);
                acc[nt] = __builtin_amdgcn_mfma_f32_16x16x32_bf16(wf[nt][kt], zlo, acc[nt], 0, 0, 0);
            }
        }

        // contiguous epilogue: lane (c,q) owns cols half*64+q*16..+16 of row r
        if (vT[tt]) {
            unsigned short* obase = Out + (size_t)rT[tt] * H + half * 64 + q * 16;
            uint4 p0, p1;
            p0.x = pack2(acc[0][0], acc[0][1]); p0.y = pack2(acc[0][2], acc[0][3]);
            p0.z = pack2(acc[1][0], acc[1][1]); p0.w = pack2(acc[1][2], acc[1][3]);
            p1.x = pack2(acc[2][0], acc[2][1]); p1.y = pack2(acc[2][2], acc[2][3]);
            p1.z = pack2(acc[3][0], acc[3][1]); p1.w = pack2(acc[3][2], acc[3][3]);
            *(uint4*)(obase)     = p0;
            *(uint4*)(obase + 8) = p1;
        }
    }
}

// ---------------------------------------------------------------------------
// edge kernel v2 (unchanged from round 8): 4-way unrolled gather.
// ---------------------------------------------------------------------------
#define EUN 4
__global__ __launch_bounds__(256) void edge_kernel(
    const unsigned short* __restrict__ U, const unsigned short* __restrict__ F,
    const int* __restrict__ row, const int* __restrict__ col,
    const float* __restrict__ W2, const float* __restrict__ b2,
    float* __restrict__ out, int E)
{
    const int lane = threadIdx.x & 15;
    const int g  = (blockIdx.x * blockDim.x + threadIdx.x) >> 4;
    const int nG = (gridDim.x * blockDim.x) >> 4;

    const float4 w2a = ((const float4*)W2)[2 * lane];
    const float4 w2b = ((const float4*)W2)[2 * lane + 1];
    const float bias = b2[0] + INF_BIAS;

    for (int e0 = g; e0 < E; e0 += EUN * nG) {
        int iu[EUN], ifo[EUN];
        #pragma unroll
        for (int i = 0; i < EUN; ++i) {
            int e  = e0 + i * nG;
            int ec = (e < E) ? e : e0;
            iu[i]  = row[ec];
            ifo[i] = col[ec];
        }
        uint4 uv[EUN], fv[EUN];
        #pragma unroll
        for (int i = 0; i < EUN; ++i) {
            uv[i] = ((const uint4*)(U + (size_t)iu[i]  * H))[lane];
            fv[i] = ((const uint4*)(F + (size_t)ifo[i] * H))[lane];
        }
        #pragma unroll
        for (int i = 0; i < EUN; ++i) {
            float2 u0 = unpack2(uv[i].x), f0 = unpack2(fv[i].x);
            float2 u1 = unpack2(uv[i].y), f1 = unpack2(fv[i].y);
            float2 u2 = unpack2(uv[i].z), f2 = unpack2(fv[i].z);
            float2 u3 = unpack2(uv[i].w), f3 = unpack2(fv[i].w);

            float s =
                w2a.x * fmaxf(u0.x + f0.x, 0.0f) +
                w2a.y * fmaxf(u0.y + f0.y, 0.0f) +
                w2a.z * fmaxf(u1.x + f1.x, 0.0f) +
                w2a.w * fmaxf(u1.y + f1.y, 0.0f) +
                w2b.x * fmaxf(u2.x + f2.x, 0.0f) +
                w2b.y * fmaxf(u2.y + f2.y, 0.0f) +
                w2b.z * fmaxf(u3.x + f3.x, 0.0f) +
                w2b.w * fmaxf(u3.y + f3.y, 0.0f);

            s += __shfl_xor(s, 8, 16);
            s += __shfl_xor(s, 4, 16);
            s += __shfl_xor(s, 2, 16);
            s += __shfl_xor(s, 1, 16);

            const int e = e0 + i * nG;
            if (lane == 0 && e < E) {
                float x = s + bias;
                out[e] = 1.0f / (1.0f + __expf(-x));
            }
        }
    }
}

extern "C" void kernel_launch(void* const* d_in, const int* in_sizes, int n_in,
                              void* d_out, int out_size, void* d_ws, size_t ws_size,
                              hipStream_t stream) {
    const float* z_user = (const float*)d_in[0];
    const float* z_food = (const float*)d_in[1];
    const int*   row    = (const int*)d_in[2];
    const int*   col    = (const int*)d_in[3];
    const float* W1     = (const float*)d_in[4];
    const float* b1     = (const float*)d_in[5];
    const float* gamma  = (const float*)d_in[6];
    const float* beta   = (const float*)d_in[7];
    const float* rm     = (const float*)d_in[8];
    const float* rv     = (const float*)d_in[9];
    const float* W2     = (const float*)d_in[10];
    const float* b2     = (const float*)d_in[11];
    float* out = (float*)d_out;

    const int n_users = in_sizes[0] / H;
    const int n_foods = in_sizes[1] / H;
    const int E       = in_sizes[2];

    // workspace layout
    unsigned short* U      = (unsigned short*)d_ws;        // n_users*128 bf16
    unsigned short* F      = U + (size_t)n_users * H;      // n_foods*128 bf16
    unsigned short* Wswz_u = F + (size_t)n_foods * H;      // 128*128 bf16, frag order
    unsigned short* Wswz_f = Wswz_u + H * H;               // 128*128 bf16, frag order
    float*          d_usr  = (float*)(Wswz_f + H * H);     // 128 f32

    prep_kernel<<<32, 64, 0, stream>>>(W1, b1, gamma, beta, rm, rv,
                                       Wswz_u, Wswz_f, d_usr);

    // 64-row (4-tile) chunk per block; waves process 2 tiles concurrently
    const int GU = ((n_users >> 4) + 3) / 4;   // 1563
    const int GF = ((n_foods >> 4) + 3) / 4;   // 782
    proj_mfma<<<GU + GF, 256, 0, stream>>>(z_user, z_food, Wswz_u, Wswz_f, d_usr,
                                           U, F, n_users, n_foods, GU);

    edge_kernel<<<8192, 256, 0, stream>>>(U, F, row, col, W2, b2, out, E);
}

// Round 11
// 205.743 us; speedup vs baseline: 1.1141x; 1.0274x over previous
//
#include <hip/hip_runtime.h>
#include <hip/hip_bf16.h>
#include <math.h>

#define H 128
#define EPS 1e-5f
#define INF_BIAS 0.1f

typedef __attribute__((ext_vector_type(8))) short bf16x8;
typedef __attribute__((ext_vector_type(4))) float f32x4;

// ---- bf16 helpers (RNE) ----
__device__ inline unsigned short f2bf_rne(float f) {
    unsigned u = __float_as_uint(f);
    u += 0x7fffu + ((u >> 16) & 1u);
    return (unsigned short)(u >> 16);
}
__device__ inline float bf2f(unsigned short h) {
    return __uint_as_float(((unsigned)h) << 16);
}
__device__ inline unsigned pack2(float a, float b) {
    return (unsigned)f2bf_rne(a) | ((unsigned)f2bf_rne(b) << 16);
}
__device__ inline float2 unpack2(unsigned v) {
    float2 r;
    r.x = __uint_as_float(v << 16);
    r.y = __uint_as_float(v & 0xffff0000u);
    return r;
}

// ---------------------------------------------------------------------------
// prep: BN-prescaled bf16 W in MFMA A-fragment order with PERMUTED j->m
// mapping (epilogue contiguity):
//   frag f = half*16 + nt*4 + kt; lane t = q*16+c holds
//   j = half*64 + (c>>2)*16 + nt*4 + (c&3), k = kt*32+q*8..+8
// ---------------------------------------------------------------------------
__global__ void prep_kernel(
    const float* __restrict__ W1, const float* __restrict__ b1,
    const float* __restrict__ gamma, const float* __restrict__ beta,
    const float* __restrict__ rm, const float* __restrict__ rv,
    unsigned short* __restrict__ Wswz_u, unsigned short* __restrict__ Wswz_f,
    float* __restrict__ d_user)
{
    const int f    = blockIdx.x;          // 0..31
    const int half = f >> 4, nt = (f >> 2) & 3, kt = f & 3;
    const int t    = threadIdx.x;         // 0..63
    const int c    = t & 15, q = t >> 4;

    const int j  = half * 64 + (c >> 2) * 16 + nt * 4 + (c & 3);
    const float a = gamma[j] * rsqrtf(rv[j] + EPS);
    const int k0 = kt * 32 + q * 8;

    unsigned short wu[8], wf[8];
    #pragma unroll
    for (int i = 0; i < 8; ++i) {
        wu[i] = f2bf_rne(a * W1[(size_t)j * (2 * H) + k0 + i]);
        wf[i] = f2bf_rne(a * W1[(size_t)j * (2 * H) + H + k0 + i]);
    }
    const size_t dst = (size_t)f * 512 + (size_t)t * 8;   // ushort units
    #pragma unroll
    for (int i = 0; i < 8; ++i) { Wswz_u[dst + i] = wu[i]; Wswz_f[dst + i] = wf[i]; }

    if (kt == 0 && q == 0) d_user[j] = a * (b1[j] - rm[j]) + beta[j];
}

// ---------------------------------------------------------------------------
// proj_mfma v8: PERSISTENT waves + register double-buffered Z prefetch.
// Wave pair (half 0/1 of same tile) strides over tiles; each wave keeps the
// NEXT tile's 8 Z-loads in flight while computing the current tile -> memory
// requests never drain (no block-generation bubbles). Per-tile arithmetic,
// W fragments, and store pattern bit-identical to R10.
// ---------------------------------------------------------------------------
__global__ __launch_bounds__(256, 2) void proj_mfma(
    const float* __restrict__ z_user, const float* __restrict__ z_food,
    const unsigned short* __restrict__ Wswz_u, const unsigned short* __restrict__ Wswz_f,
    const float* __restrict__ d_user,
    unsigned short* __restrict__ U, unsigned short* __restrict__ F,
    int n_users, int n_foods, int GU, int GB)
{
    const bool userMode = (blockIdx.x < (unsigned)GU);
    const float* Z;
    const unsigned short* Wsrc;
    unsigned short* Out;
    int n, blk0, nblk;
    if (userMode) { Z = z_user; Wsrc = Wswz_u; Out = U; n = n_users; blk0 = blockIdx.x;      nblk = GU; }
    else          { Z = z_food; Wsrc = Wswz_f; Out = F; n = n_foods; blk0 = blockIdx.x - GU; nblk = GB - GU; }
    const int tiles = n >> 4;               // n divisible by 16

    const int wave = threadIdx.x >> 6;
    const int lane = threadIdx.x & 63;
    const int c = lane & 15;                // row within tile
    const int q = lane >> 4;                // k-group / 16-col subgroup
    const int wg   = blk0 * 4 + wave;       // global wave id within mode
    const int half = wg & 1;                // 64-col half
    const int pair = wg >> 1;               // tile-pair id
    const int stride = nblk * 2;            // tile stride between iterations

    // ---- preload this wave's 16 W fragments (64 VGPR), L2-hot
    bf16x8 wf[4][4];
    #pragma unroll
    for (int nt = 0; nt < 4; ++nt)
        #pragma unroll
        for (int kt = 0; kt < 4; ++kt)
            wf[nt][kt] = *(const bf16x8*)(Wsrc + (size_t)(half * 16 + nt * 4 + kt) * 512 + lane * 8);

    // ---- BN offset (accumulator init values)
    f32x4 dvec[4];
    #pragma unroll
    for (int nt = 0; nt < 4; ++nt) {
        if (userMode) {
            float4 d = *(const float4*)(d_user + half * 64 + q * 16 + nt * 4);
            dvec[nt] = (f32x4){d.x, d.y, d.z, d.w};
        } else {
            dvec[nt] = (f32x4){0.f, 0.f, 0.f, 0.f};
        }
    }

    // ---- Z tile load (clamped address; 8 x 16B per lane)
    auto loadZ = [&](int t, float4 zb[8]) {
        const float* zrow = Z + (size_t)(min(t, tiles - 1) * 16 + c) * H;
        #pragma unroll
        for (int kt = 0; kt < 4; ++kt) {
            const int k0 = kt * 32 + q * 8;
            zb[2 * kt + 0] = ((const float4*)(zrow + k0))[0];
            zb[2 * kt + 1] = ((const float4*)(zrow + k0))[1];
        }
    };

    // ---- compute + guarded store (bit-identical per-tile math to R10)
    auto computeStore = [&](int t, const float4 zb[8]) {
        f32x4 acc[4];
        #pragma unroll
        for (int nt = 0; nt < 4; ++nt) acc[nt] = dvec[nt];

        #pragma unroll
        for (int kt = 0; kt < 4; ++kt) {
            float4 za = zb[2 * kt + 0];
            float4 zv = zb[2 * kt + 1];
            bf16x8 zhi, zlo;
            {
                float v[8] = {za.x, za.y, za.z, za.w, zv.x, zv.y, zv.z, zv.w};
                #pragma unroll
                for (int i = 0; i < 8; ++i) {
                    unsigned short hi = f2bf_rne(v[i]);
                    unsigned short lo = f2bf_rne(v[i] - bf2f(hi));
                    zhi[i] = (short)hi; zlo[i] = (short)lo;
                }
            }
            #pragma unroll
            for (int nt = 0; nt < 4; ++nt) {
                acc[nt] = __builtin_amdgcn_mfma_f32_16x16x32_bf16(wf[nt][kt], zhi, acc[nt], 0, 0, 0);
                acc[nt] = __builtin_amdgcn_mfma_f32_16x16x32_bf16(wf[nt][kt], zlo, acc[nt], 0, 0, 0);
            }
        }

        if (t < tiles) {
            const int r = t * 16 + c;
            unsigned short* obase = Out + (size_t)r * H + half * 64 + q * 16;
            uint4 p0, p1;
            p0.x = pack2(acc[0][0], acc[0][1]); p0.y = pack2(acc[0][2], acc[0][3]);
            p0.z = pack2(acc[1][0], acc[1][1]); p0.w = pack2(acc[1][2], acc[1][3]);
            p1.x = pack2(acc[2][0], acc[2][1]); p1.y = pack2(acc[2][2], acc[2][3]);
            p1.z = pack2(acc[3][0], acc[3][1]); p1.w = pack2(acc[3][2], acc[3][3]);
            *(uint4*)(obase)     = p0;
            *(uint4*)(obase + 8) = p1;
        }
    };

    int nIt = (tiles + stride - 1) / stride;
    nIt = (nIt + 1) & ~1;                   // even, for 2x unrolled pipeline

    float4 zb0[8], zb1[8];
    int t = pair;
    loadZ(t, zb0);
    for (int it = 0; it < nIt; it += 2) {
        loadZ(t + stride, zb1);             // prefetch next while computing cur
        computeStore(t, zb0);
        if (it + 2 < nIt) loadZ(t + 2 * stride, zb0);
        computeStore(t + stride, zb1);
        t += 2 * stride;
    }
}

// ---------------------------------------------------------------------------
// edge kernel v2 (unchanged from round 8): 4-way unrolled gather.
// ---------------------------------------------------------------------------
#define EUN 4
__global__ __launch_bounds__(256) void edge_kernel(
    const unsigned short* __restrict__ U, const unsigned short* __restrict__ F,
    const int* __restrict__ row, const int* __restrict__ col,
    const float* __restrict__ W2, const float* __restrict__ b2,
    float* __restrict__ out, int E)
{
    const int lane = threadIdx.x & 15;
    const int g  = (blockIdx.x * blockDim.x + threadIdx.x) >> 4;
    const int nG = (gridDim.x * blockDim.x) >> 4;

    const float4 w2a = ((const float4*)W2)[2 * lane];
    const float4 w2b = ((const float4*)W2)[2 * lane + 1];
    const float bias = b2[0] + INF_BIAS;

    for (int e0 = g; e0 < E; e0 += EUN * nG) {
        int iu[EUN], ifo[EUN];
        #pragma unroll
        for (int i = 0; i < EUN; ++i) {
            int e  = e0 + i * nG;
            int ec = (e < E) ? e : e0;
            iu[i]  = row[ec];
            ifo[i] = col[ec];
        }
        uint4 uv[EUN], fv[EUN];
        #pragma unroll
        for (int i = 0; i < EUN; ++i) {
            uv[i] = ((const uint4*)(U + (size_t)iu[i]  * H))[lane];
            fv[i] = ((const uint4*)(F + (size_t)ifo[i] * H))[lane];
        }
        #pragma unroll
        for (int i = 0; i < EUN; ++i) {
            float2 u0 = unpack2(uv[i].x), f0 = unpack2(fv[i].x);
            float2 u1 = unpack2(uv[i].y), f1 = unpack2(fv[i].y);
            float2 u2 = unpack2(uv[i].z), f2 = unpack2(fv[i].z);
            float2 u3 = unpack2(uv[i].w), f3 = unpack2(fv[i].w);

            float s =
                w2a.x * fmaxf(u0.x + f0.x, 0.0f) +
                w2a.y * fmaxf(u0.y + f0.y, 0.0f) +
                w2a.z * fmaxf(u1.x + f1.x, 0.0f) +
                w2a.w * fmaxf(u1.y + f1.y, 0.0f) +
                w2b.x * fmaxf(u2.x + f2.x, 0.0f) +
                w2b.y * fmaxf(u2.y + f2.y, 0.0f) +
                w2b.z * fmaxf(u3.x + f3.x, 0.0f) +
                w2b.w * fmaxf(u3.y + f3.y, 0.0f);

            s += __shfl_xor(s, 8, 16);
            s += __shfl_xor(s, 4, 16);
            s += __shfl_xor(s, 2, 16);
            s += __shfl_xor(s, 1, 16);

            const int e = e0 + i * nG;
            if (lane == 0 && e < E) {
                float x = s + bias;
                out[e] = 1.0f / (1.0f + __expf(-x));
            }
        }
    }
}

extern "C" void kernel_launch(void* const* d_in, const int* in_sizes, int n_in,
                              void* d_out, int out_size, void* d_ws, size_t ws_size,
                              hipStream_t stream) {
    const float* z_user = (const float*)d_in[0];
    const float* z_food = (const float*)d_in[1];
    const int*   row    = (const int*)d_in[2];
    const int*   col    = (const int*)d_in[3];
    const float* W1     = (const float*)d_in[4];
    const float* b1     = (const float*)d_in[5];
    const float* gamma  = (const float*)d_in[6];
    const float* beta   = (const float*)d_in[7];
    const float* rm     = (const float*)d_in[8];
    const float* rv     = (const float*)d_in[9];
    const float* W2     = (const float*)d_in[10];
    const float* b2     = (const float*)d_in[11];
    float* out = (float*)d_out;

    const int n_users = in_sizes[0] / H;
    const int n_foods = in_sizes[1] / H;
    const int E       = in_sizes[2];

    // workspace layout
    unsigned short* U      = (unsigned short*)d_ws;        // n_users*128 bf16
    unsigned short* F      = U + (size_t)n_users * H;      // n_foods*128 bf16
    unsigned short* Wswz_u = F + (size_t)n_foods * H;      // 128*128 bf16, frag order
    unsigned short* Wswz_f = Wswz_u + H * H;               // 128*128 bf16, frag order
    float*          d_usr  = (float*)(Wswz_f + H * H);     // 128 f32

    prep_kernel<<<32, 64, 0, stream>>>(W1, b1, gamma, beta, rm, rv,
                                       Wswz_u, Wswz_f, d_usr);

    // persistent: ~2 blocks/CU, 2:1 user:food split matches row ratio
    const int GU = 342, GB = 512;
    proj_mfma<<<GB, 256, 0, stream>>>(z_user, z_food, Wswz_u, Wswz_f, d_usr,
                                      U, F, n_users, n_foods, GU, GB);

    edge_kernel<<<8192, 256, 0, stream>>>(U, F, row, col, W2, b2, out, E);
}